// Round 3
// baseline (162.216 us; speedup 1.0000x reference)
//
#include <hip/hip_runtime.h>

// HMM posterior: out[b,t,s] = log_softmax_s(alphahat[t]+betahat[t]) — batch-independent
// (per-(b,t) emission scalars cancel in the state-axis softmax; observations unused).
// Linear space with per-row max-rescale (scale cancels): p_t = p0 E^t, q_t = E^(1023-t) 1.
//
// K1 hmm_scan (ONE block, 4 waves): doubling scan with split-bf16 MFMA.
//   Keep planes = E^(2^k) (hi/lo bf16, row-major + transposed). For k = 0..9:
//     P rows [2^k, 2^(k+1)) = P rows [0, 2^k) @ E^(2^k)      (B-frags from Th/Tl)
//     Q rows [2^k, 2^(k+1)) = Q rows [0, 2^k) @ (E^(2^k))^T  (B-frags from Ah/Al)
//     planes <- norm(E^(2^k) squared)                         (as before)
//   Rows written 16-granular; "garbage" rows from padding are provably overwritten
//   by the valid write (step floor(log2 r)) before any valid row consumes them, and
//   never corrupt valid rows (row-to-row independent, per-row rescale).
//   ~4080 MFMA total on one CU ≈ 4 µs — replaces hmm_powers AND all per-t chains.
// K2 hmm_out (1024 blocks): NO matvecs — gv = log P[t] + log Q[1023-t], log-softmax
//   row, broadcast-write 64 KB. Write-roofline bound.

#define TT 1024
#define NK 10
#define PS 72   // bf16 plane stride in ushorts (144 B rows: 16B-aligned, 2-way banks = free)

typedef short  bf16x8 __attribute__((ext_vector_type(8)));
typedef float  f32x4  __attribute__((ext_vector_type(4)));

__device__ __forceinline__ unsigned short f2bf(float x) {
    unsigned u = __float_as_uint(x);
    unsigned r = u + 0x7fffu + ((u >> 16) & 1u);   // RNE; valid data finite
    return (unsigned short)(r >> 16);
}
__device__ __forceinline__ float bf2f(unsigned short h) {
    return __uint_as_float(((unsigned)h) << 16);
}

__global__ __launch_bounds__(256) void hmm_scan(const float* __restrict__ logA,
                                                const float* __restrict__ logInit,
                                                unsigned short* __restrict__ Ph,
                                                unsigned short* __restrict__ Pl,
                                                unsigned short* __restrict__ Qh,
                                                unsigned short* __restrict__ Ql,
                                                float* __restrict__ Pf,
                                                float* __restrict__ Qf) {
    __shared__ unsigned short Ah[64 * PS], Al[64 * PS];   // E^(2^k) row-major hi/lo
    __shared__ unsigned short Th[64 * PS], Tl[64 * PS];   // E^(2^k) transposed hi/lo
    __shared__ float red4[4];
    const int tid  = threadIdx.x;
    const int wid  = tid >> 6;
    const int lane = tid & 63;

    // ---- Phase 0: E0 = exp(logA), normalized by max entry -> planes.
    {
        const int row = tid >> 2;
        const int c0  = (tid & 3) * 16;
        float v[16];
        float lmax = 0.f;
        #pragma unroll
        for (int jj = 0; jj < 4; ++jj) {
            float4 x = ((const float4*)logA)[row * 16 + (tid & 3) * 4 + jj];
            float e0 = __expf(x.x), e1 = __expf(x.y), e2 = __expf(x.z), e3 = __expf(x.w);
            v[4 * jj + 0] = e0; v[4 * jj + 1] = e1; v[4 * jj + 2] = e2; v[4 * jj + 3] = e3;
            lmax = fmaxf(lmax, fmaxf(fmaxf(e0, e1), fmaxf(e2, e3)));
        }
        #pragma unroll
        for (int off = 32; off > 0; off >>= 1)
            lmax = fmaxf(lmax, __shfl_xor(lmax, off, 64));
        if (lane == 0) red4[wid] = lmax;
        __syncthreads();
        const float sc = 1.f / fmaxf(fmaxf(red4[0], red4[1]), fmaxf(red4[2], red4[3]));
        #pragma unroll
        for (int j = 0; j < 16; ++j) {
            float val = v[j] * sc;
            unsigned short hi = f2bf(val);
            unsigned short lo = f2bf(val - bf2f(hi));
            int cc = c0 + j;
            Ah[row * PS + cc] = hi;  Al[row * PS + cc] = lo;
            Th[cc * PS + row] = hi;  Tl[cc * PS + row] = lo;
        }
    }

    // ---- Row 0 of P (p0, rescaled) and Q (ones).
    if (tid < 64) {
        float p = __expf(logInit[tid]);
        float mx = p;
        #pragma unroll
        for (int off = 32; off > 0; off >>= 1)
            mx = fmaxf(mx, __shfl_xor(mx, off, 64));
        float val = p * (1.f / mx);
        unsigned short hi = f2bf(val);
        Pf[tid] = val;  Ph[tid] = hi;  Pl[tid] = f2bf(val - bf2f(hi));
    } else if (tid < 128) {
        int s = tid & 63;
        Qf[s] = 1.f;  Qh[s] = 0x3F80u;  Ql[s] = 0;
    }

    const int quad = lane >> 4;
    const int l15  = lane & 15;

    for (int k = 0; k < NK; ++k) {
        __syncthreads();                 // planes = E^(2^k); all prior P/Q rows visible

        // ---- doubling GEMMs: new rows [2^k, 2^(k+1)) for P and Q, 16-row tiles.
        const int ntP = (k <= 4) ? 1 : (1 << (k - 4));
        const int nt  = ntP << 1;
        for (int tt2 = wid; tt2 < nt; tt2 += 4) {
            const int isQ = (tt2 >= ntP) ? 1 : 0;
            const int tau = isQ ? (tt2 - ntP) : tt2;
            const unsigned short* Sh = isQ ? Qh : Ph;
            const unsigned short* Sl = isQ ? Ql : Pl;
            const unsigned short* Bh = isQ ? Ah : Th;   // B-frag reads rows of B^T
            const unsigned short* Bl = isQ ? Al : Tl;
            f32x4 acc[4];
            #pragma unroll
            for (int c = 0; c < 4; ++c) acc[c] = (f32x4){0.f, 0.f, 0.f, 0.f};
            #pragma unroll
            for (int kk = 0; kk < 2; ++kk) {
                const int arow = tau * 16 + l15;
                const int ko   = 32 * kk + quad * 8;
                bf16x8 ah = *(const bf16x8*)&Sh[(arow << 6) + ko];
                bf16x8 al = *(const bf16x8*)&Sl[(arow << 6) + ko];
                #pragma unroll
                for (int c = 0; c < 4; ++c) {
                    bf16x8 bh = *(const bf16x8*)&Bh[(16 * c + l15) * PS + ko];
                    bf16x8 bl = *(const bf16x8*)&Bl[(16 * c + l15) * PS + ko];
                    acc[c] = __builtin_amdgcn_mfma_f32_16x16x32_bf16(ah, bh, acc[c], 0, 0, 0);
                    acc[c] = __builtin_amdgcn_mfma_f32_16x16x32_bf16(ah, bl, acc[c], 0, 0, 0);
                    acc[c] = __builtin_amdgcn_mfma_f32_16x16x32_bf16(al, bh, acc[c], 0, 0, 0);
                }
            }
            // per-row max rescale (row = quad*4 + r lives in the 16 lanes of this quad)
            float rs[4];
            #pragma unroll
            for (int r = 0; r < 4; ++r) {
                float m = fmaxf(fmaxf(acc[0][r], acc[1][r]), fmaxf(acc[2][r], acc[3][r]));
                #pragma unroll
                for (int off = 8; off > 0; off >>= 1)
                    m = fmaxf(m, __shfl_xor(m, off, 64));
                rs[r] = 1.f / m;
            }
            unsigned short* Dh = isQ ? Qh : Ph;
            unsigned short* Dl = isQ ? Ql : Pl;
            float*          Df = isQ ? Qf : Pf;
            const int gb = (1 << k) + tau * 16 + quad * 4;
            #pragma unroll
            for (int c = 0; c < 4; ++c) {
                #pragma unroll
                for (int r = 0; r < 4; ++r) {
                    float val = acc[c][r] * rs[r];
                    const int idx = ((gb + r) << 6) + 16 * c + l15;
                    Df[idx] = val;
                    if (k < NK - 1) {                 // hi/lo only needed as future A-operand
                        unsigned short hi = f2bf(val);
                        Dh[idx] = hi;  Dl[idx] = f2bf(val - bf2f(hi));
                    }
                }
            }
        }

        if (k == NK - 1) break;

        // ---- squaring: planes <- norm(E^(2^k)^2), split-bf16 MFMA (24/wave).
        f32x4 acc[4];
        #pragma unroll
        for (int c = 0; c < 4; ++c) acc[c] = (f32x4){0.f, 0.f, 0.f, 0.f};
        #pragma unroll
        for (int kk = 0; kk < 2; ++kk) {
            const int ao = (16 * wid + l15) * PS + 32 * kk + quad * 8;
            bf16x8 ah = *(const bf16x8*)&Ah[ao];
            bf16x8 al = *(const bf16x8*)&Al[ao];
            #pragma unroll
            for (int c = 0; c < 4; ++c) {
                const int bo = (16 * c + l15) * PS + 32 * kk + quad * 8;
                bf16x8 bh = *(const bf16x8*)&Th[bo];
                bf16x8 bl = *(const bf16x8*)&Tl[bo];
                acc[c] = __builtin_amdgcn_mfma_f32_16x16x32_bf16(ah, bh, acc[c], 0, 0, 0);
                acc[c] = __builtin_amdgcn_mfma_f32_16x16x32_bf16(ah, bl, acc[c], 0, 0, 0);
                acc[c] = __builtin_amdgcn_mfma_f32_16x16x32_bf16(al, bh, acc[c], 0, 0, 0);
            }
        }
        float m = 0.f;
        #pragma unroll
        for (int c = 0; c < 4; ++c)
            #pragma unroll
            for (int r = 0; r < 4; ++r) m = fmaxf(m, acc[c][r]);
        #pragma unroll
        for (int off = 32; off > 0; off >>= 1)
            m = fmaxf(m, __shfl_xor(m, off, 64));
        if (lane == 0) red4[wid] = m;
        __syncthreads();                 // ALL plane reads this step done; red4 ready
        const float sc = 1.f / fmaxf(fmaxf(red4[0], red4[1]), fmaxf(red4[2], red4[3]));
        #pragma unroll
        for (int c = 0; c < 4; ++c) {
            #pragma unroll
            for (int r = 0; r < 4; ++r) {
                float val = acc[c][r] * sc;
                const int rr = 16 * wid + quad * 4 + r;   // C/D: row = quad*4+reg (m89)
                const int cc = 16 * c   + l15;            //      col = lane&15
                unsigned short hi = f2bf(val);
                unsigned short lo = f2bf(val - bf2f(hi));
                Ah[rr * PS + cc] = hi;  Al[rr * PS + cc] = lo;
                Th[cc * PS + rr] = hi;  Tl[cc * PS + rr] = lo;
            }
        }
    }
}

// 1024 blocks x 256 threads: NO matvecs. gv = log P[t] + log Q[1023-t]; log-softmax
// the 64-row; broadcast-write row t to all 256 batches (64 KB/block).
__global__ __launch_bounds__(256) void hmm_out(const float* __restrict__ Pf,
                                               const float* __restrict__ Qf,
                                               float* __restrict__ out) {
    const int t   = blockIdx.x;
    const int tid = threadIdx.x;
    __shared__ float sgr[64];

    if (tid < 64) {
        float p = Pf[(t << 6) + tid];
        float q = Qf[(((TT - 1) - t) << 6) + tid];
        float gv = __logf(p) + __logf(q);
        float mx = gv;
        #pragma unroll
        for (int off = 32; off > 0; off >>= 1)
            mx = fmaxf(mx, __shfl_xor(mx, off, 64));
        float ex = __expf(gv - mx);
        float sm = ex;
        #pragma unroll
        for (int off = 32; off > 0; off >>= 1)
            sm += __shfl_xor(sm, off, 64);
        sgr[tid] = gv - mx - __logf(sm);
    }
    __syncthreads();

    const int s4 = tid & 15;
    const int b0 = tid >> 4;                 // 0..15
    float4 val = ((const float4*)sgr)[s4];
    float4* o4 = (float4*)out;
    const size_t trow = (size_t)t * 16 + s4;
    #pragma unroll
    for (int it = 0; it < 16; ++it) {
        int b = (it << 4) + b0;
        o4[(size_t)b * 16384 + trow] = val;
    }
}

extern "C" void kernel_launch(void* const* d_in, const int* in_sizes, int n_in,
                              void* d_out, int out_size, void* d_ws, size_t ws_size,
                              hipStream_t stream) {
    // inputs: [0] observations (unused), [1] log_transition (64x64 f32),
    //         [2] log_initial (64 f32), [3] log_emission (unused)
    const float* logA    = (const float*)d_in[1];
    const float* logInit = (const float*)d_in[2];
    unsigned short* Ph = (unsigned short*)d_ws;      // 1024*64 ushort = 128 KB
    unsigned short* Pl = Ph + (TT * 64);
    unsigned short* Qh = Pl + (TT * 64);
    unsigned short* Ql = Qh + (TT * 64);
    float* Pf = (float*)(Ql + (TT * 64));            // 1024*64 f32 = 256 KB
    float* Qf = Pf + (TT * 64);
    hmm_scan<<<1, 256, 0, stream>>>(logA, logInit, Ph, Pl, Qh, Ql, Pf, Qf);
    hmm_out<<<TT, 256, 0, stream>>>(Pf, Qf, (float*)d_out);
}

// Round 4
// 101.170 us; speedup vs baseline: 1.6034x; 1.6034x over previous
//
#include <hip/hip_runtime.h>

// HMM posterior: out[b,t,s] = log_softmax_s(alphahat[t]+betahat[t]) — batch-independent
// (per-(b,t) emission scalars cancel in the state-axis softmax; observations unused).
// Linear space: p_t = p0 E^t, q_t = E^(1023-t) 1, E = exp(logA)/max. Global scale of
// p,q cancels in the final log-softmax, so NO per-step rescale is needed anywhere in
// the per-t chains (p <= 64^10 * e^4 ~ 2^66, fp32-safe; no underflow: per-step min
// shrink factor >= e^-3.2 for N(0,1) logA).
//
// K1 hmm_powers_par: 10 BLOCKS; block b redundantly computes squarings 1..b entirely
//   in LDS (split-bf16 MFMA, no intermediate global stores -> no vmcnt drain at the
//   per-squaring barriers — the measured killer of the serial version) and writes only
//   M[2^b], Mt[2^b] once at the end. Critical path = block 9 ~ 9 x ~0.5 us.
//   All blocks compute bit-identical intermediates -> tables identical to round-0.
// K2 hmm_fused: 1024 blocks x 128 thr; wave0 p-chain (M rows), wave1 q-chain (Mt rows),
//   binary decomposition of t / 1023-t, NO per-step reductions; log-softmax row;
//   broadcast scatter-write 64 KB/block (measured ~4.3 TB/s — fine).

#define TT 1024
#define NK 10
#define PS 72   // bf16 plane stride in ushorts (144 B rows: 16B-aligned, 2-way banks = free)

typedef short  bf16x8 __attribute__((ext_vector_type(8)));
typedef float  f32x4  __attribute__((ext_vector_type(4)));

__device__ __forceinline__ unsigned short f2bf(float x) {
    unsigned u = __float_as_uint(x);
    unsigned r = u + 0x7fffu + ((u >> 16) & 1u);   // RNE; inputs finite
    return (unsigned short)(r >> 16);
}
__device__ __forceinline__ float bf2f(unsigned short h) {
    return __uint_as_float(((unsigned)h) << 16);
}

__global__ __launch_bounds__(256) void hmm_powers_par(const float* __restrict__ logA,
                                                      float* __restrict__ M,
                                                      float* __restrict__ Mt) {
    __shared__ unsigned short Ah[64 * PS], Al[64 * PS];   // row-major hi/lo planes
    __shared__ unsigned short Th[64 * PS], Tl[64 * PS];   // transposed hi/lo planes
    __shared__ float red4[4];
    const int lvl  = blockIdx.x;        // this block produces M[lvl] = E^(2^lvl)
    const int tid  = threadIdx.x;
    const int wid  = tid >> 6;
    const int lane = tid & 63;

    // ---- Phase 0 (identical in all blocks): E0 = exp(logA)/max -> regs (+ planes).
    const int row = tid >> 2;
    const int c0  = (tid & 3) * 16;
    float v[16];
    {
        float lmax = 0.f;
        #pragma unroll
        for (int jj = 0; jj < 4; ++jj) {
            float4 x = ((const float4*)logA)[row * 16 + (tid & 3) * 4 + jj];
            float e0 = __expf(x.x), e1 = __expf(x.y), e2 = __expf(x.z), e3 = __expf(x.w);
            v[4 * jj + 0] = e0; v[4 * jj + 1] = e1; v[4 * jj + 2] = e2; v[4 * jj + 3] = e3;
            lmax = fmaxf(lmax, fmaxf(fmaxf(e0, e1), fmaxf(e2, e3)));
        }
        #pragma unroll
        for (int off = 32; off > 0; off >>= 1)
            lmax = fmaxf(lmax, __shfl_xor(lmax, off, 64));
        if (lane == 0) red4[wid] = lmax;
        __syncthreads();
        const float sc = 1.f / fmaxf(fmaxf(red4[0], red4[1]), fmaxf(red4[2], red4[3]));

        if (lvl == 0) {                 // block 0: write E directly, done.
            #pragma unroll
            for (int j = 0; j < 16; ++j) {
                float val = v[j] * sc;
                int cc = c0 + j;
                M [row * 64 + cc] = val;
                Mt[cc * 64 + row] = val;
            }
            return;
        }
        #pragma unroll
        for (int j = 0; j < 16; ++j) {
            float val = v[j] * sc;
            unsigned short hi = f2bf(val);
            unsigned short lo = f2bf(val - bf2f(hi));
            int cc = c0 + j;
            Ah[row * PS + cc] = hi;  Al[row * PS + cc] = lo;
            Th[cc * PS + row] = hi;  Tl[cc * PS + row] = lo;
        }
    }

    const int quad = lane >> 4;
    const int l15  = lane & 15;

    // ---- squarings 1..lvl, all-LDS; only the last writes global (single drain).
    for (int k = 1; k <= lvl; ++k) {
        __syncthreads();                       // planes = E^(2^(k-1))
        f32x4 acc[4];
        #pragma unroll
        for (int c = 0; c < 4; ++c) acc[c] = (f32x4){0.f, 0.f, 0.f, 0.f};
        #pragma unroll
        for (int kk = 0; kk < 2; ++kk) {
            const int ao = (16 * wid + l15) * PS + 32 * kk + quad * 8;
            bf16x8 ah = *(const bf16x8*)&Ah[ao];
            bf16x8 al = *(const bf16x8*)&Al[ao];
            #pragma unroll
            for (int c = 0; c < 4; ++c) {
                const int bo = (16 * c + l15) * PS + 32 * kk + quad * 8;
                bf16x8 bh = *(const bf16x8*)&Th[bo];
                bf16x8 bl = *(const bf16x8*)&Tl[bo];
                acc[c] = __builtin_amdgcn_mfma_f32_16x16x32_bf16(ah, bh, acc[c], 0, 0, 0);
                acc[c] = __builtin_amdgcn_mfma_f32_16x16x32_bf16(ah, bl, acc[c], 0, 0, 0);
                acc[c] = __builtin_amdgcn_mfma_f32_16x16x32_bf16(al, bh, acc[c], 0, 0, 0);
            }
        }
        float m = 0.f;
        #pragma unroll
        for (int c = 0; c < 4; ++c)
            #pragma unroll
            for (int r = 0; r < 4; ++r) m = fmaxf(m, acc[c][r]);
        #pragma unroll
        for (int off = 32; off > 0; off >>= 1)
            m = fmaxf(m, __shfl_xor(m, off, 64));
        if (lane == 0) red4[wid] = m;
        __syncthreads();                       // frag reads done by all waves; red4 ready
        const float sc = 1.f / fmaxf(fmaxf(red4[0], red4[1]), fmaxf(red4[2], red4[3]));

        if (k < lvl) {                         // rewrite planes (LDS only — no drain)
            #pragma unroll
            for (int c = 0; c < 4; ++c) {
                #pragma unroll
                for (int r = 0; r < 4; ++r) {
                    float val = acc[c][r] * sc;
                    const int rr = 16 * wid + quad * 4 + r;   // C/D: row = quad*4+reg (m89)
                    const int cc = 16 * c   + l15;            //      col = lane&15
                    unsigned short hi = f2bf(val);
                    unsigned short lo = f2bf(val - bf2f(hi));
                    Ah[rr * PS + cc] = hi;  Al[rr * PS + cc] = lo;
                    Th[cc * PS + rr] = hi;  Tl[cc * PS + rr] = lo;
                }
            }
        } else {                               // final level: single global write
            float* Mk  = M  + (lvl << 12);
            float* Mtk = Mt + (lvl << 12);
            #pragma unroll
            for (int c = 0; c < 4; ++c) {
                #pragma unroll
                for (int r = 0; r < 4; ++r) {
                    float val = acc[c][r] * sc;
                    const int rr = 16 * wid + quad * 4 + r;
                    const int cc = 16 * c   + l15;
                    Mk [rr * 64 + cc] = val;
                    Mtk[cc * 64 + rr] = val;
                }
            }
        }
    }
}

// 1024 blocks x 128 threads: wave 0 -> p-chain, wave 1 -> q-chain (no per-step
// reductions), log-softmax row, broadcast-write 64 KB to all 256 batches.
__global__ __launch_bounds__(128) void hmm_fused(const float* __restrict__ M,
                                                 const float* __restrict__ Mt,
                                                 const float* __restrict__ logInit,
                                                 float* __restrict__ out) {
    const int t = blockIdx.x;
    __shared__ float sp[64];
    __shared__ float sq[64];
    __shared__ float sgr[64];
    const int lane = threadIdx.x & 63;
    const int w    = threadIdx.x >> 6;

    if (w == 0) {
        sp[lane] = __expf(logInit[lane]);
        const int e = t;
        for (int k = 0; k < NK; ++k) {
            if ((e >> k) & 1) {
                const float* Mk = M + (k << 12);
                float a0 = 0.f, a1 = 0.f, a2 = 0.f, a3 = 0.f;
                #pragma unroll
                for (int i = 0; i < 16; ++i) {
                    a0 = fmaf(sp[i],      Mk[( i       << 6) + lane], a0);
                    a1 = fmaf(sp[i + 16], Mk[((i + 16) << 6) + lane], a1);
                    a2 = fmaf(sp[i + 32], Mk[((i + 32) << 6) + lane], a2);
                    a3 = fmaf(sp[i + 48], Mk[((i + 48) << 6) + lane], a3);
                }
                sp[lane] = (a0 + a1) + (a2 + a3);   // no rescale: scale cancels in softmax
            }
        }
    } else {
        sq[lane] = 1.f;
        const int e = (TT - 1) - t;
        for (int k = 0; k < NK; ++k) {
            if ((e >> k) & 1) {
                const float* Mk = Mt + (k << 12);
                float a0 = 0.f, a1 = 0.f, a2 = 0.f, a3 = 0.f;
                #pragma unroll
                for (int i = 0; i < 16; ++i) {
                    a0 = fmaf(sq[i],      Mk[( i       << 6) + lane], a0);
                    a1 = fmaf(sq[i + 16], Mk[((i + 16) << 6) + lane], a1);
                    a2 = fmaf(sq[i + 32], Mk[((i + 32) << 6) + lane], a2);
                    a3 = fmaf(sq[i + 48], Mk[((i + 48) << 6) + lane], a3);
                }
                sq[lane] = (a0 + a1) + (a2 + a3);
            }
        }
    }
    __syncthreads();

    if (w == 0) {
        float gv = __logf(sp[lane]) + __logf(sq[lane]);
        float mx = gv;
        #pragma unroll
        for (int off = 32; off > 0; off >>= 1)
            mx = fmaxf(mx, __shfl_xor(mx, off, 64));
        float ex = __expf(gv - mx);
        float sm = ex;
        #pragma unroll
        for (int off = 32; off > 0; off >>= 1)
            sm += __shfl_xor(sm, off, 64);
        sgr[lane] = gv - mx - __logf(sm);
    }
    __syncthreads();

    // Broadcast row t to all 256 batches: out[b][t][0..63], 256-B chunks, float4.
    const int s4 = threadIdx.x & 15;
    const int b0 = threadIdx.x >> 4;                 // 0..7
    float4 val = ((const float4*)sgr)[s4];
    float4* o4 = (float4*)out;
    const size_t trow = (size_t)t * 16 + s4;
    #pragma unroll
    for (int it = 0; it < 32; ++it) {
        int b = (it << 3) + b0;
        o4[(size_t)b * 16384 + trow] = val;
    }
}

extern "C" void kernel_launch(void* const* d_in, const int* in_sizes, int n_in,
                              void* d_out, int out_size, void* d_ws, size_t ws_size,
                              hipStream_t stream) {
    // inputs: [0] observations (unused), [1] log_transition (64x64 f32),
    //         [2] log_initial (64 f32), [3] log_emission (unused)
    const float* logA    = (const float*)d_in[1];
    const float* logInit = (const float*)d_in[2];
    float* M  = (float*)d_ws;              // 10 * 4096 floats
    float* Mt = M + NK * 4096;             // 10 * 4096 floats (320 KB of ws)
    hmm_powers_par<<<NK, 256, 0, stream>>>(logA, M, Mt);
    hmm_fused<<<TT, 128, 0, stream>>>(M, Mt, logInit, (float*)d_out);
}